// Round 1
// baseline (7967.613 us; speedup 1.0000x reference)
//
#include <hip/hip_runtime.h>
#include <math.h>

#define NN   100000
#define GG   100
#define FIN  12
#define FOUT 32
#define KD   5
#define CC   4
#define EE   1600000
#define ROWS 108          // 9 blocks * 12 features

// ---------------- utility kernels ----------------

__global__ void k_zero(float* __restrict__ p, int n) {
    int i = blockIdx.x * 256 + threadIdx.x;
    if (i < n) p[i] = 0.f;
}

__global__ void k_deg(const int* __restrict__ ei, const float* __restrict__ w,
                      float* __restrict__ deg_out, float* __restrict__ deg_in) {
    int e = blockIdx.x * 256 + threadIdx.x;
    if (e >= EE) return;
    int s = ei[e];
    int d = ei[EE + e];
    float we = w[e];
    atomicAdd(deg_out + s, we);
    atomicAdd(deg_in + d, we);
}

__global__ void k_inv(float* __restrict__ p, int n) {
    int i = blockIdx.x * 256 + threadIdx.x;
    if (i < n) p[i] = 1.f / p[i];
}

// Collapse W[2,K,44,32] -> effective [108,32] (only first 12 input rows matter;
// block 0 = W[0,0]+W[1,0]; blocks 1..4 = W[0,k]; blocks 5..8 = W[1,k]).
__global__ void k_buildw(const float* __restrict__ Wz_in, const float* __restrict__ Wh_in,
                         float* __restrict__ Wz, float* __restrict__ Wh) {
    int t = blockIdx.x * 256 + threadIdx.x;
    if (t >= 2 * ROWS * FOUT) return;
    int sel = t / (ROWS * FOUT);
    int rem = t - sel * ROWS * FOUT;
    int r = rem / FOUT;
    int f = rem - r * FOUT;
    int b = r / 12;
    int i = r - b * 12;
    const float* Ws = sel ? Wh_in : Wz_in;
    float v;
    if (b == 0)
        v = Ws[(0 * KD + 0) * 44 * 32 + i * 32 + f] + Ws[(1 * KD + 0) * 44 * 32 + i * 32 + f];
    else if (b <= 4)
        v = Ws[(0 * KD + b) * 44 * 32 + i * 32 + f];
    else
        v = Ws[(1 * KD + (b - 4)) * 44 * 32 + i * 32 + f];
    (sel ? Wh : Wz)[r * FOUT + f] = v;
}

// Initialize the scatter destinations: 0 for step 1, -T_{k-2} for steps >= 2
// (fuses the Chebyshev "2*prop - T_prev" combine).
__global__ void k_init_step(float4* __restrict__ outF, float4* __restrict__ outR,
                            const float4* __restrict__ prevF, const float4* __restrict__ prevR) {
    int i = blockIdx.x * 256 + threadIdx.x;
    if (i >= NN * FIN / 4) return;
    if (prevF) {
        float4 a = prevF[i];
        outF[i] = make_float4(-a.x, -a.y, -a.z, -a.w);
        float4 b = prevR[i];
        outR[i] = make_float4(-b.x, -b.y, -b.z, -b.w);
    } else {
        float4 z = make_float4(0.f, 0.f, 0.f, 0.f);
        outF[i] = z;
        outR[i] = z;
    }
}

// Edge-parallel scatter for both diffusion directions.
// fwd: out[dst] += c * deg_out_inv[src] * h[src]
// rev: out[src] += c * deg_in_inv[src]  * h[dst]
__global__ void k_scatter(const int* __restrict__ ei,
                          const float* __restrict__ dinv_out, const float* __restrict__ dinv_in,
                          const float* __restrict__ inF, const float* __restrict__ inR,
                          float* __restrict__ outF, float* __restrict__ outR,
                          float c, int nbF) {
    bool rev = (int)blockIdx.x >= nbF;
    int e = (rev ? (int)blockIdx.x - nbF : (int)blockIdx.x) * 256 + threadIdx.x;
    if (e >= EE) return;
    int s = ei[e];
    int d = ei[EE + e];
    const float* in;
    float* out;
    float wv;
    if (!rev) {
        wv = c * dinv_out[s];
        in = inF + (size_t)s * FIN;
        out = outF + (size_t)d * FIN;
    } else {
        wv = c * dinv_in[s];
        in = inR + (size_t)d * FIN;
        out = outR + (size_t)s * FIN;
    }
    float4 h0 = *(const float4*)(in);
    float4 h1 = *(const float4*)(in + 4);
    float4 h2 = *(const float4*)(in + 8);
    atomicAdd(out + 0,  wv * h0.x);
    atomicAdd(out + 1,  wv * h0.y);
    atomicAdd(out + 2,  wv * h0.z);
    atomicAdd(out + 3,  wv * h0.w);
    atomicAdd(out + 4,  wv * h1.x);
    atomicAdd(out + 5,  wv * h1.y);
    atomicAdd(out + 6,  wv * h1.z);
    atomicAdd(out + 7,  wv * h1.w);
    atomicAdd(out + 8,  wv * h2.x);
    atomicAdd(out + 9,  wv * h2.y);
    atomicAdd(out + 10, wv * h2.z);
    atomicAdd(out + 11, wv * h2.w);
}

__global__ void k_init_out(float* __restrict__ out, const float* __restrict__ b_lin) {
    int t = blockIdx.x * 256 + threadIdx.x;
    if (t < GG * CC) out[t] = b_lin[t & 3];
}

// Per-node: [1x108] @ [108x32] for z and h_tilde, gate, ReLU, @W_lin,
// block-reduce over 250 nodes (each block owns 1/4 of one graph) -> atomicAdd.
__global__ __launch_bounds__(256) void k_fused(
        const float* __restrict__ x, const float* __restrict__ TS,
        const float* __restrict__ Wz, const float* __restrict__ Wh,
        const float* __restrict__ bz, const float* __restrict__ bh,
        const float* __restrict__ Wlin, float* __restrict__ out) {
    int g = blockIdx.x >> 2;
    int seg = blockIdx.x & 3;
    int tid = threadIdx.x;
    int node = g * 1000 + seg * 250 + tid;
    bool active = tid < 250;

    float az[FOUT], ah[FOUT];
#pragma unroll
    for (int f = 0; f < FOUT; ++f) { az[f] = bz[f]; ah[f] = bh[f]; }
    float o[CC] = {0.f, 0.f, 0.f, 0.f};

    if (active) {
        for (int b = 0; b < 9; ++b) {
            const float* row = (b == 0) ? (x + (size_t)node * FIN)
                                        : (TS + ((size_t)(b - 1) * NN + node) * FIN);
            float4 r0 = *(const float4*)(row);
            float4 r1 = *(const float4*)(row + 4);
            float4 r2 = *(const float4*)(row + 8);
            float rv[FIN] = {r0.x, r0.y, r0.z, r0.w, r1.x, r1.y, r1.z, r1.w,
                             r2.x, r2.y, r2.z, r2.w};
            const float* wzr = Wz + b * 12 * FOUT;
            const float* whr = Wh + b * 12 * FOUT;
#pragma unroll
            for (int i = 0; i < FIN; ++i) {
                float v = rv[i];
#pragma unroll
                for (int f = 0; f < FOUT; ++f) {
                    az[f] = fmaf(v, wzr[i * FOUT + f], az[f]);
                    ah[f] = fmaf(v, whr[i * FOUT + f], ah[f]);
                }
            }
        }
#pragma unroll
        for (int f = 0; f < FOUT; ++f) {
            float z = 1.f / (1.f + __expf(-az[f]));
            float e2 = __expf(2.f * ah[f]);
            float th = 1.f - 2.f / (e2 + 1.f);   // tanh, overflow-safe
            float hv = (1.f - z) * th;
            hv = fmaxf(hv, 0.f);
#pragma unroll
            for (int c = 0; c < CC; ++c) o[c] = fmaf(hv, Wlin[f * 4 + c], o[c]);
        }
    }

    __shared__ float red[256 * CC];
#pragma unroll
    for (int c = 0; c < CC; ++c) red[tid * CC + c] = o[c];
    __syncthreads();
    for (int st = 128; st > 0; st >>= 1) {
        if (tid < st) {
#pragma unroll
            for (int c = 0; c < CC; ++c) red[tid * CC + c] += red[(tid + st) * CC + c];
        }
        __syncthreads();
    }
    if (tid == 0) {
#pragma unroll
        for (int c = 0; c < CC; ++c) atomicAdd(out + g * CC + c, red[c] * 0.001f);
    }
}

// ---------------- launch ----------------

extern "C" void kernel_launch(void* const* d_in, const int* in_sizes, int n_in,
                              void* d_out, int out_size, void* d_ws, size_t ws_size,
                              hipStream_t stream) {
    const float* x     = (const float*)d_in[0];
    const int*   ei    = (const int*)d_in[1];
    const float* ew    = (const float*)d_in[2];
    // d_in[3] (batch) unused: graphs are exactly 1000 contiguous nodes
    const float* W_z   = (const float*)d_in[4];
    const float* b_z   = (const float*)d_in[5];
    // d_in[6], d_in[7] (W_r, b_r) unused: R only multiplies the zero hidden state
    const float* W_h   = (const float*)d_in[8];
    const float* b_h   = (const float*)d_in[9];
    const float* W_lin = (const float*)d_in[10];
    const float* b_lin = (const float*)d_in[11];
    float* out = (float*)d_out;

    float* ws      = (float*)d_ws;
    float* deg_out = ws;                       // N   (becomes 1/deg_out)
    float* deg_in  = ws + NN;                  // N   (becomes 1/deg_in)
    float* TS      = ws + 2 * NN;              // 8 * N * 12 diffusion blocks
    float* Wz      = TS + (size_t)8 * NN * FIN;
    float* Wh      = Wz + ROWS * FOUT;

    float* T1o = TS + (size_t)0 * NN * FIN;
    float* T2o = TS + (size_t)1 * NN * FIN;
    float* T3o = TS + (size_t)2 * NN * FIN;
    float* T4o = TS + (size_t)3 * NN * FIN;
    float* T1i = TS + (size_t)4 * NN * FIN;
    float* T2i = TS + (size_t)5 * NN * FIN;
    float* T3i = TS + (size_t)6 * NN * FIN;
    float* T4i = TS + (size_t)7 * NN * FIN;

    dim3 B(256);
    int nbF = (EE + 255) / 256;                 // blocks per direction in scatter
    int nbI = (NN * FIN / 4 + 255) / 256;       // float4 init blocks

    k_zero<<<(2 * NN + 255) / 256, B, 0, stream>>>(deg_out, 2 * NN);
    k_deg<<<nbF, B, 0, stream>>>(ei, ew, deg_out, deg_in);
    k_inv<<<(2 * NN + 255) / 256, B, 0, stream>>>(deg_out, 2 * NN);
    k_buildw<<<(2 * ROWS * FOUT + 255) / 256, B, 0, stream>>>(W_z, W_h, Wz, Wh);

    // step 1: T1 = prop(Xc)
    k_init_step<<<nbI, B, 0, stream>>>((float4*)T1o, (float4*)T1i, nullptr, nullptr);
    k_scatter<<<2 * nbF, B, 0, stream>>>(ei, deg_out, deg_in, x, x, T1o, T1i, 1.f, nbF);
    // step 2: T2 = 2*prop(T1) - Xc
    k_init_step<<<nbI, B, 0, stream>>>((float4*)T2o, (float4*)T2i, (const float4*)x, (const float4*)x);
    k_scatter<<<2 * nbF, B, 0, stream>>>(ei, deg_out, deg_in, T1o, T1i, T2o, T2i, 2.f, nbF);
    // step 3: T3 = 2*prop(T2) - T1
    k_init_step<<<nbI, B, 0, stream>>>((float4*)T3o, (float4*)T3i, (const float4*)T1o, (const float4*)T1i);
    k_scatter<<<2 * nbF, B, 0, stream>>>(ei, deg_out, deg_in, T2o, T2i, T3o, T3i, 2.f, nbF);
    // step 4: T4 = 2*prop(T3) - T2
    k_init_step<<<nbI, B, 0, stream>>>((float4*)T4o, (float4*)T4i, (const float4*)T2o, (const float4*)T2i);
    k_scatter<<<2 * nbF, B, 0, stream>>>(ei, deg_out, deg_in, T3o, T3i, T4o, T4i, 2.f, nbF);

    k_init_out<<<(GG * CC + 255) / 256, B, 0, stream>>>(out, b_lin);
    k_fused<<<4 * GG, B, 0, stream>>>(x, TS, Wz, Wh, b_z, b_h, W_lin, out);
}

// Round 2
// 1037.869 us; speedup vs baseline: 7.6769x; 7.6769x over previous
//
#include <hip/hip_runtime.h>
#include <math.h>

#define NN   100000
#define GG   100
#define FIN  12
#define FOUT 32
#define KD   5
#define CC   4
#define EE   1600000
#define ROWS 108          // 9 blocks * 12 features

// ---------------- utility kernels ----------------

__global__ void k_zero(int* __restrict__ p, int n) {
    int i = blockIdx.x * 256 + threadIdx.x;
    if (i < n) p[i] = 0;
}

// Weighted degrees (float atomics) + CSR bucket counts (int atomics).
// fwd CSR keyed by dst (gather for prop_fwd), rev CSR keyed by src.
__global__ void k_deg(const int* __restrict__ ei, const float* __restrict__ w,
                      float* __restrict__ deg_out, float* __restrict__ deg_in,
                      int* __restrict__ cnt) {
    int e = blockIdx.x * 256 + threadIdx.x;
    if (e >= EE) return;
    int s = ei[e];
    int d = ei[EE + e];
    float we = w[e];
    atomicAdd(deg_out + s, we);
    atomicAdd(deg_in + d, we);
    atomicAdd(cnt + d, 1);        // fwd: in-edges of d
    atomicAdd(cnt + NN + s, 1);   // rev: out-edges of s
}

__global__ void k_inv(float* __restrict__ p, int n) {
    int i = blockIdx.x * 256 + threadIdx.x;
    if (i < n) p[i] = 1.f / p[i];
}

// ---- 3-kernel exclusive scan over cnt[0..n) -> off[0..n], off[n]=total ----

__global__ __launch_bounds__(1024) void k_scan1(const int* __restrict__ cnt,
                                                int* __restrict__ off,
                                                int* __restrict__ bsum, int n) {
    __shared__ int sh[1024];
    int t = threadIdx.x;
    int i = blockIdx.x * 1024 + t;
    int v = (i < n) ? cnt[i] : 0;
    sh[t] = v;
    __syncthreads();
    for (int d = 1; d < 1024; d <<= 1) {
        int x = sh[t];
        if (t >= d) x += sh[t - d];
        __syncthreads();
        sh[t] = x;
        __syncthreads();
    }
    int incl = sh[t];
    if (i < n) off[i] = incl - v;          // block-local exclusive
    if (t == 1023) bsum[blockIdx.x] = incl;
}

__global__ __launch_bounds__(256) void k_scan2(int* __restrict__ bsum,
                                               int* __restrict__ off, int n, int nb) {
    __shared__ int sh[256];
    int t = threadIdx.x;
    int v = (t < nb) ? bsum[t] : 0;
    sh[t] = v;
    __syncthreads();
    for (int d = 1; d < 256; d <<= 1) {
        int x = sh[t];
        if (t >= d) x += sh[t - d];
        __syncthreads();
        sh[t] = x;
        __syncthreads();
    }
    int incl = sh[t];
    if (t < nb) bsum[t] = incl - v;        // exclusive block base
    if (t == nb - 1) off[n] = incl;        // grand total (= 2*EE)
}

__global__ __launch_bounds__(1024) void k_scan3(int* __restrict__ off,
                                                const int* __restrict__ bsum, int n) {
    int i = blockIdx.x * 1024 + threadIdx.x;
    if (i < n) off[i] += bsum[blockIdx.x];
}

__global__ void k_initcur(int* __restrict__ cur, const int* __restrict__ off, int n) {
    int i = blockIdx.x * 256 + threadIdx.x;
    if (i < n) cur[i] = off[i];
}

// Fill CSR records: {neighbor index, 1/deg coefficient} per edge, per direction.
// NOTE: reference propagation uses 1/deg only — edge weight enters degrees only.
__global__ void k_fill(const int* __restrict__ ei,
                       const float* __restrict__ dinv_out, const float* __restrict__ dinv_in,
                       int* __restrict__ cur, int2* __restrict__ rec) {
    int e = blockIdx.x * 256 + threadIdx.x;
    if (e >= EE) return;
    int s = ei[e];
    int d = ei[EE + e];
    int p1 = atomicAdd(cur + d, 1);
    rec[p1] = make_int2(s, __float_as_int(dinv_out[s]));
    int p2 = atomicAdd(cur + NN + s, 1);
    rec[p2] = make_int2(d, __float_as_int(dinv_in[s]));
}

// Collapse W[2,K,44,32] -> effective [108,32] (only first 12 input rows matter;
// block 0 = W[0,0]+W[1,0]; blocks 1..4 = W[0,k]; blocks 5..8 = W[1,k]).
__global__ void k_buildw(const float* __restrict__ Wz_in, const float* __restrict__ Wh_in,
                         float* __restrict__ Wz, float* __restrict__ Wh) {
    int t = blockIdx.x * 256 + threadIdx.x;
    if (t >= 2 * ROWS * FOUT) return;
    int sel = t / (ROWS * FOUT);
    int rem = t - sel * ROWS * FOUT;
    int r = rem / FOUT;
    int f = rem - r * FOUT;
    int b = r / 12;
    int i = r - b * 12;
    const float* Ws = sel ? Wh_in : Wz_in;
    float v;
    if (b == 0)
        v = Ws[(0 * KD + 0) * 44 * 32 + i * 32 + f] + Ws[(1 * KD + 0) * 44 * 32 + i * 32 + f];
    else if (b <= 4)
        v = Ws[(0 * KD + b) * 44 * 32 + i * 32 + f];
    else
        v = Ws[(1 * KD + (b - 4)) * 44 * 32 + i * 32 + f];
    (sel ? Wh : Wz)[r * FOUT + f] = v;
}

// Gather-based diffusion step for both directions, Chebyshev combine fused:
//   out = c * sum_{edges} coef * h[nbr] - prev   (prev==null -> 0)
__global__ __launch_bounds__(256) void k_gather(
        const int* __restrict__ off, const int2* __restrict__ rec,
        const float* __restrict__ inF, const float* __restrict__ inR,
        const float* __restrict__ prevF, const float* __restrict__ prevR,
        float* __restrict__ outF, float* __restrict__ outR, float c) {
    int gid = blockIdx.x * 256 + threadIdx.x;
    if (gid >= 2 * NN) return;
    bool rev = gid >= NN;
    int node = rev ? gid - NN : gid;
    const float* h = rev ? inR : inF;
    const float* prev = rev ? prevR : prevF;
    float* out = rev ? outR : outF;

    int e0 = off[gid], e1 = off[gid + 1];
    float a[FIN];
#pragma unroll
    for (int f = 0; f < FIN; ++f) a[f] = 0.f;

    for (int e = e0; e < e1; ++e) {
        int2 r = rec[e];
        float w = __int_as_float(r.y);
        const float4* row = (const float4*)(h + (size_t)r.x * FIN);
        float4 x0 = row[0], x1 = row[1], x2 = row[2];
        a[0] = fmaf(w, x0.x, a[0]);  a[1] = fmaf(w, x0.y, a[1]);
        a[2] = fmaf(w, x0.z, a[2]);  a[3] = fmaf(w, x0.w, a[3]);
        a[4] = fmaf(w, x1.x, a[4]);  a[5] = fmaf(w, x1.y, a[5]);
        a[6] = fmaf(w, x1.z, a[6]);  a[7] = fmaf(w, x1.w, a[7]);
        a[8] = fmaf(w, x2.x, a[8]);  a[9] = fmaf(w, x2.y, a[9]);
        a[10] = fmaf(w, x2.z, a[10]); a[11] = fmaf(w, x2.w, a[11]);
    }

    float4* o = (float4*)(out + (size_t)node * FIN);
    if (prev) {
        const float4* p = (const float4*)(prev + (size_t)node * FIN);
        float4 p0 = p[0], p1 = p[1], p2 = p[2];
        o[0] = make_float4(c * a[0] - p0.x, c * a[1] - p0.y, c * a[2] - p0.z, c * a[3] - p0.w);
        o[1] = make_float4(c * a[4] - p1.x, c * a[5] - p1.y, c * a[6] - p1.z, c * a[7] - p1.w);
        o[2] = make_float4(c * a[8] - p2.x, c * a[9] - p2.y, c * a[10] - p2.z, c * a[11] - p2.w);
    } else {
        o[0] = make_float4(a[0], a[1], a[2], a[3]);
        o[1] = make_float4(a[4], a[5], a[6], a[7]);
        o[2] = make_float4(a[8], a[9], a[10], a[11]);
    }
}

__global__ void k_init_out(float* __restrict__ out, const float* __restrict__ b_lin) {
    int t = blockIdx.x * 256 + threadIdx.x;
    if (t < GG * CC) out[t] = b_lin[t & 3];
}

// Per-node: [1x108] @ [108x32] for z and h_tilde, gate, ReLU, @W_lin,
// block-reduce over 250 nodes (each block owns 1/4 of one graph) -> atomicAdd.
__global__ __launch_bounds__(256) void k_fused(
        const float* __restrict__ x, const float* __restrict__ TS,
        const float* __restrict__ Wz, const float* __restrict__ Wh,
        const float* __restrict__ bz, const float* __restrict__ bh,
        const float* __restrict__ Wlin, float* __restrict__ out) {
    int g = blockIdx.x >> 2;
    int seg = blockIdx.x & 3;
    int tid = threadIdx.x;
    int node = g * 1000 + seg * 250 + tid;
    bool active = tid < 250;

    float az[FOUT], ah[FOUT];
#pragma unroll
    for (int f = 0; f < FOUT; ++f) { az[f] = bz[f]; ah[f] = bh[f]; }
    float o[CC] = {0.f, 0.f, 0.f, 0.f};

    if (active) {
        for (int b = 0; b < 9; ++b) {
            const float* row = (b == 0) ? (x + (size_t)node * FIN)
                                        : (TS + ((size_t)(b - 1) * NN + node) * FIN);
            float4 r0 = *(const float4*)(row);
            float4 r1 = *(const float4*)(row + 4);
            float4 r2 = *(const float4*)(row + 8);
            float rv[FIN] = {r0.x, r0.y, r0.z, r0.w, r1.x, r1.y, r1.z, r1.w,
                             r2.x, r2.y, r2.z, r2.w};
            const float* wzr = Wz + b * 12 * FOUT;
            const float* whr = Wh + b * 12 * FOUT;
#pragma unroll
            for (int i = 0; i < FIN; ++i) {
                float v = rv[i];
#pragma unroll
                for (int f = 0; f < FOUT; ++f) {
                    az[f] = fmaf(v, wzr[i * FOUT + f], az[f]);
                    ah[f] = fmaf(v, whr[i * FOUT + f], ah[f]);
                }
            }
        }
#pragma unroll
        for (int f = 0; f < FOUT; ++f) {
            float z = 1.f / (1.f + __expf(-az[f]));
            float e2 = __expf(2.f * ah[f]);
            float th = 1.f - 2.f / (e2 + 1.f);   // tanh, overflow-safe
            float hv = (1.f - z) * th;
            hv = fmaxf(hv, 0.f);
#pragma unroll
            for (int c = 0; c < CC; ++c) o[c] = fmaf(hv, Wlin[f * 4 + c], o[c]);
        }
    }

    __shared__ float red[256 * CC];
#pragma unroll
    for (int c = 0; c < CC; ++c) red[tid * CC + c] = o[c];
    __syncthreads();
    for (int st = 128; st > 0; st >>= 1) {
        if (tid < st) {
#pragma unroll
            for (int c = 0; c < CC; ++c) red[tid * CC + c] += red[(tid + st) * CC + c];
        }
        __syncthreads();
    }
    if (tid == 0) {
#pragma unroll
        for (int c = 0; c < CC; ++c) atomicAdd(out + g * CC + c, red[c] * 0.001f);
    }
}

// ---------------- launch ----------------

extern "C" void kernel_launch(void* const* d_in, const int* in_sizes, int n_in,
                              void* d_out, int out_size, void* d_ws, size_t ws_size,
                              hipStream_t stream) {
    const float* x     = (const float*)d_in[0];
    const int*   ei    = (const int*)d_in[1];
    const float* ew    = (const float*)d_in[2];
    // d_in[3] (batch) unused: graphs are exactly 1000 contiguous nodes
    const float* W_z   = (const float*)d_in[4];
    const float* b_z   = (const float*)d_in[5];
    // d_in[6], d_in[7] (W_r, b_r) unused: R only multiplies the zero hidden state
    const float* W_h   = (const float*)d_in[8];
    const float* b_h   = (const float*)d_in[9];
    const float* W_lin = (const float*)d_in[10];
    const float* b_lin = (const float*)d_in[11];
    float* out = (float*)d_out;

    // ---- workspace layout (rec first for 8B alignment) ----
    int2*  rec     = (int2*)d_ws;                       // 2*EE records
    float* deg_out = (float*)(rec + 2 * (size_t)EE);    // N
    float* deg_in  = deg_out + NN;                      // N
    int*   cnt     = (int*)(deg_in + NN);               // 2N
    int*   off     = cnt + 2 * NN;                      // 2N+1
    int*   cur     = off + 2 * NN + 1;                  // 2N
    int*   bsum    = cur + 2 * NN;                      // 256
    float* Wz      = (float*)(bsum + 256);              // 108*32
    float* Wh      = Wz + ROWS * FOUT;                  // 108*32
    float* TS      = Wh + ROWS * FOUT;                  // 8*N*12

    float* T1o = TS + (size_t)0 * NN * FIN;
    float* T2o = TS + (size_t)1 * NN * FIN;
    float* T3o = TS + (size_t)2 * NN * FIN;
    float* T4o = TS + (size_t)3 * NN * FIN;
    float* T1i = TS + (size_t)4 * NN * FIN;
    float* T2i = TS + (size_t)5 * NN * FIN;
    float* T3i = TS + (size_t)6 * NN * FIN;
    float* T4i = TS + (size_t)7 * NN * FIN;

    dim3 B(256);
    int nbE = (EE + 255) / 256;
    int nScan = 2 * NN;                       // concatenated fwd+rev counts
    int nbS = (nScan + 1023) / 1024;          // 196 scan blocks
    int nbG = (2 * NN + 255) / 256;           // gather blocks

    // zero degrees (float bits) + counts: contiguous 4N words
    k_zero<<<(4 * NN + 255) / 256, B, 0, stream>>>((int*)deg_out, 4 * NN);
    k_deg<<<nbE, B, 0, stream>>>(ei, ew, deg_out, deg_in, cnt);
    k_inv<<<(2 * NN + 255) / 256, B, 0, stream>>>(deg_out, 2 * NN);

    // CSR offsets via exclusive scan of cnt[0..2N)
    k_scan1<<<nbS, 1024, 0, stream>>>(cnt, off, bsum, nScan);
    k_scan2<<<1, 256, 0, stream>>>(bsum, off, nScan, nbS);
    k_scan3<<<nbS, 1024, 0, stream>>>(off, bsum, nScan);
    k_initcur<<<(2 * NN + 255) / 256, B, 0, stream>>>(cur, off, 2 * NN);
    k_fill<<<nbE, B, 0, stream>>>(ei, deg_out, deg_in, cur, rec);

    k_buildw<<<(2 * ROWS * FOUT + 255) / 256, B, 0, stream>>>(W_z, W_h, Wz, Wh);

    // Chebyshev diffusion basis via gather (atomic-free)
    k_gather<<<nbG, B, 0, stream>>>(off, rec, x, x, nullptr, nullptr, T1o, T1i, 1.f);
    k_gather<<<nbG, B, 0, stream>>>(off, rec, T1o, T1i, x, x, T2o, T2i, 2.f);
    k_gather<<<nbG, B, 0, stream>>>(off, rec, T2o, T2i, T1o, T1i, T3o, T3i, 2.f);
    k_gather<<<nbG, B, 0, stream>>>(off, rec, T3o, T3i, T2o, T2i, T4o, T4i, 2.f);

    k_init_out<<<(GG * CC + 255) / 256, B, 0, stream>>>(out, b_lin);
    k_fused<<<4 * GG, B, 0, stream>>>(x, TS, Wz, Wh, b_z, b_h, W_lin, out);
}

// Round 3
// 941.036 us; speedup vs baseline: 8.4669x; 1.1029x over previous
//
#include <hip/hip_runtime.h>
#include <math.h>

#define NN   100000
#define GG   100
#define FIN  12
#define FOUT 32
#define KD   5
#define CC   4
#define EE   1600000
#define ROWS 108          // 9 blocks * 12 features

// ---------------- CSR build ----------------

__global__ void k_zero(int* __restrict__ p, int n) {
    int i = blockIdx.x * 256 + threadIdx.x;
    if (i < n) p[i] = 0;
}

// CSR bucket counts only (int atomics; float degrees come later, atomic-free).
// fwd CSR keyed by dst (gather for prop_fwd), rev CSR keyed by src.
__global__ void k_cnt(const int* __restrict__ ei, int* __restrict__ cnt) {
    int e = blockIdx.x * 256 + threadIdx.x;
    if (e >= EE) return;
    atomicAdd(cnt + ei[EE + e], 1);       // fwd: in-edges of dst
    atomicAdd(cnt + NN + ei[e], 1);       // rev: out-edges of src
}

// ---- 3-kernel exclusive scan over cnt[0..n) -> off[0..n], off[n]=total ----

__global__ __launch_bounds__(1024) void k_scan1(const int* __restrict__ cnt,
                                                int* __restrict__ off,
                                                int* __restrict__ bsum, int n) {
    __shared__ int sh[1024];
    int t = threadIdx.x;
    int i = blockIdx.x * 1024 + t;
    int v = (i < n) ? cnt[i] : 0;
    sh[t] = v;
    __syncthreads();
    for (int d = 1; d < 1024; d <<= 1) {
        int x = sh[t];
        if (t >= d) x += sh[t - d];
        __syncthreads();
        sh[t] = x;
        __syncthreads();
    }
    int incl = sh[t];
    if (i < n) off[i] = incl - v;          // block-local exclusive
    if (t == 1023) bsum[blockIdx.x] = incl;
}

__global__ __launch_bounds__(256) void k_scan2(int* __restrict__ bsum,
                                               int* __restrict__ off, int n, int nb) {
    __shared__ int sh[256];
    int t = threadIdx.x;
    int v = (t < nb) ? bsum[t] : 0;
    sh[t] = v;
    __syncthreads();
    for (int d = 1; d < 256; d <<= 1) {
        int x = sh[t];
        if (t >= d) x += sh[t - d];
        __syncthreads();
        sh[t] = x;
        __syncthreads();
    }
    int incl = sh[t];
    if (t < nb) bsum[t] = incl - v;        // exclusive block base
    if (t == nb - 1) off[n] = incl;        // grand total (= 2*EE)
}

// adds block base AND seeds the fill cursors (replaces separate initcur pass)
__global__ __launch_bounds__(1024) void k_scan3(int* __restrict__ off, int* __restrict__ cur,
                                                const int* __restrict__ bsum, int n) {
    int i = blockIdx.x * 1024 + threadIdx.x;
    if (i < n) {
        int v = off[i] + bsum[blockIdx.x];
        off[i] = v;
        cur[i] = v;
    }
}

// Fill CSR records {neighbor, edge_weight}.
__global__ void k_fill(const int* __restrict__ ei, const float* __restrict__ ew,
                       int* __restrict__ cur, int2* __restrict__ rec) {
    int e = blockIdx.x * 256 + threadIdx.x;
    if (e >= EE) return;
    int s = ei[e];
    int d = ei[EE + e];
    float w = ew[e];
    int p1 = atomicAdd(cur + d, 1);
    rec[p1] = make_int2(s, __float_as_int(w));
    int p2 = atomicAdd(cur + NN + s, 1);
    rec[p2] = make_int2(d, __float_as_int(w));
}

// Atomic-free degree sums from the CSR buckets:
//   fwd bucket of n (in-edges)  -> deg_in[n];  rev bucket of n (out-edges) -> deg_out[n]
__global__ void k_degsum(const int* __restrict__ off, const int2* __restrict__ rec,
                         float* __restrict__ dinv_in, float* __restrict__ dinv_out) {
    int i = blockIdx.x * 256 + threadIdx.x;
    if (i >= 2 * NN) return;
    int e0 = off[i], e1 = off[i + 1];
    const float* rf = (const float*)rec;
    float s = 0.f;
    for (int e = e0; e < e1; ++e) s += rf[2 * e + 1];
    float inv = 1.f / s;
    if (i < NN) dinv_in[i] = inv;
    else        dinv_out[i - NN] = inv;
}

// Rewrite fwd-region records' payload to the propagation coefficient 1/deg_out[src].
// Fwd region is statically rec[0..EE): every edge contributes exactly one fwd record.
// (Rev coefficient 1/deg_in[node] is uniform per output node -> applied in gather epilogue.)
__global__ void k_coef(int2* __restrict__ rec, const float* __restrict__ dinv_out) {
    int e = blockIdx.x * 256 + threadIdx.x;
    if (e >= EE) return;
    rec[e].y = __float_as_int(dinv_out[rec[e].x]);
}

// ---------------- weights ----------------

// Collapse W[2,K,44,32] -> effective [108,32] (only first 12 input rows matter;
// block 0 = W[0,0]+W[1,0]; blocks 1..4 = W[0,k]; blocks 5..8 = W[1,k]).
__global__ void k_buildw(const float* __restrict__ Wz_in, const float* __restrict__ Wh_in,
                         float* __restrict__ Wz, float* __restrict__ Wh) {
    int t = blockIdx.x * 256 + threadIdx.x;
    if (t >= 2 * ROWS * FOUT) return;
    int sel = t / (ROWS * FOUT);
    int rem = t - sel * ROWS * FOUT;
    int r = rem / FOUT;
    int f = rem - r * FOUT;
    int b = r / 12;
    int i = r - b * 12;
    const float* Ws = sel ? Wh_in : Wz_in;
    float v;
    if (b == 0)
        v = Ws[(0 * KD + 0) * 44 * 32 + i * 32 + f] + Ws[(1 * KD + 0) * 44 * 32 + i * 32 + f];
    else if (b <= 4)
        v = Ws[(0 * KD + b) * 44 * 32 + i * 32 + f];
    else
        v = Ws[(1 * KD + (b - 4)) * 44 * 32 + i * 32 + f];
    (sel ? Wh : Wz)[r * FOUT + f] = v;
}

// ---------------- diffusion gather ----------------

// Thread per (node, direction, 4-feature chunk): 6N threads total.
// fwd: out[n] = c * sum_{in-edges} coef(src) * in[src]        - prev[n]
// rev: out[n] = c * dinv_in[n] * sum_{out-edges} in[dst]      - prev[n]
__global__ __launch_bounds__(256) void k_gather(
        const int* __restrict__ off, const int2* __restrict__ rec,
        const float* __restrict__ inF, const float* __restrict__ inR,
        const float* __restrict__ prevF, const float* __restrict__ prevR,
        const float* __restrict__ dinv_in,
        float* __restrict__ outF, float* __restrict__ outR, float c) {
    int gid = blockIdx.x * 256 + threadIdx.x;
    if (gid >= 6 * NN) return;
    bool rev = gid >= 3 * NN;
    int t = rev ? gid - 3 * NN : gid;
    int node = t / 3;
    int ch = t - node * 3;
    int b = rev ? NN + node : node;
    int e0 = off[b], e1 = off[b + 1];

    float ax = 0.f, ay = 0.f, az = 0.f, aw = 0.f;
    if (rev) {
        const int* rx = (const int*)rec;
        for (int e = e0; e < e1; ++e) {
            int nbr = rx[2 * e];
            float4 v = *(const float4*)(inR + (size_t)nbr * FIN + ch * 4);
            ax += v.x; ay += v.y; az += v.z; aw += v.w;
        }
        float sc = c * dinv_in[node];
        ax *= sc; ay *= sc; az *= sc; aw *= sc;
    } else {
        for (int e = e0; e < e1; ++e) {
            int2 r = rec[e];
            float w = __int_as_float(r.y);
            float4 v = *(const float4*)(inF + (size_t)r.x * FIN + ch * 4);
            ax = fmaf(w, v.x, ax); ay = fmaf(w, v.y, ay);
            az = fmaf(w, v.z, az); aw = fmaf(w, v.w, aw);
        }
        ax *= c; ay *= c; az *= c; aw *= c;
    }

    size_t o = (size_t)node * FIN + ch * 4;
    float4 res;
    if (prevF) {
        float4 p = *(const float4*)((rev ? prevR : prevF) + o);
        res = make_float4(ax - p.x, ay - p.y, az - p.z, aw - p.w);
    } else {
        res = make_float4(ax, ay, az, aw);
    }
    *(float4*)((rev ? outR : outF) + o) = res;
}

// ---------------- epilogue ----------------

__global__ void k_init_out(float* __restrict__ out, const float* __restrict__ b_lin) {
    int t = blockIdx.x * 256 + threadIdx.x;
    if (t < GG * CC) out[t] = b_lin[t & 3];
}

// Per-node: [1x108] @ [108x32] for z and h_tilde, gate, ReLU, @W_lin,
// block-reduce over 250 nodes (each block owns 1/4 of one graph) -> atomicAdd.
__global__ __launch_bounds__(256) void k_fused(
        const float* __restrict__ x, const float* __restrict__ TS,
        const float* __restrict__ Wz, const float* __restrict__ Wh,
        const float* __restrict__ bz, const float* __restrict__ bh,
        const float* __restrict__ Wlin, float* __restrict__ out) {
    int g = blockIdx.x >> 2;
    int seg = blockIdx.x & 3;
    int tid = threadIdx.x;
    int node = g * 1000 + seg * 250 + tid;
    bool active = tid < 250;

    float az[FOUT], ah[FOUT];
#pragma unroll
    for (int f = 0; f < FOUT; ++f) { az[f] = bz[f]; ah[f] = bh[f]; }
    float o[CC] = {0.f, 0.f, 0.f, 0.f};

    if (active) {
        for (int b = 0; b < 9; ++b) {
            const float* row = (b == 0) ? (x + (size_t)node * FIN)
                                        : (TS + ((size_t)(b - 1) * NN + node) * FIN);
            float4 r0 = *(const float4*)(row);
            float4 r1 = *(const float4*)(row + 4);
            float4 r2 = *(const float4*)(row + 8);
            float rv[FIN] = {r0.x, r0.y, r0.z, r0.w, r1.x, r1.y, r1.z, r1.w,
                             r2.x, r2.y, r2.z, r2.w};
            const float* wzr = Wz + b * 12 * FOUT;
            const float* whr = Wh + b * 12 * FOUT;
#pragma unroll
            for (int i = 0; i < FIN; ++i) {
                float v = rv[i];
#pragma unroll
                for (int f = 0; f < FOUT; ++f) {
                    az[f] = fmaf(v, wzr[i * FOUT + f], az[f]);
                    ah[f] = fmaf(v, whr[i * FOUT + f], ah[f]);
                }
            }
        }
#pragma unroll
        for (int f = 0; f < FOUT; ++f) {
            float z = 1.f / (1.f + __expf(-az[f]));
            float e2 = __expf(2.f * ah[f]);
            float th = 1.f - 2.f / (e2 + 1.f);   // tanh, overflow-safe
            float hv = (1.f - z) * th;
            hv = fmaxf(hv, 0.f);
#pragma unroll
            for (int c = 0; c < CC; ++c) o[c] = fmaf(hv, Wlin[f * 4 + c], o[c]);
        }
    }

    __shared__ float red[256 * CC];
#pragma unroll
    for (int c = 0; c < CC; ++c) red[tid * CC + c] = o[c];
    __syncthreads();
    for (int st = 128; st > 0; st >>= 1) {
        if (tid < st) {
#pragma unroll
            for (int c = 0; c < CC; ++c) red[tid * CC + c] += red[(tid + st) * CC + c];
        }
        __syncthreads();
    }
    if (tid == 0) {
#pragma unroll
        for (int c = 0; c < CC; ++c) atomicAdd(out + g * CC + c, red[c] * 0.001f);
    }
}

// ---------------- launch ----------------

extern "C" void kernel_launch(void* const* d_in, const int* in_sizes, int n_in,
                              void* d_out, int out_size, void* d_ws, size_t ws_size,
                              hipStream_t stream) {
    const float* x     = (const float*)d_in[0];
    const int*   ei    = (const int*)d_in[1];
    const float* ew    = (const float*)d_in[2];
    // d_in[3] (batch) unused: graphs are exactly 1000 contiguous nodes
    const float* W_z   = (const float*)d_in[4];
    const float* b_z   = (const float*)d_in[5];
    // d_in[6], d_in[7] (W_r, b_r) unused: R only multiplies the zero hidden state
    const float* W_h   = (const float*)d_in[8];
    const float* b_h   = (const float*)d_in[9];
    const float* W_lin = (const float*)d_in[10];
    const float* b_lin = (const float*)d_in[11];
    float* out = (float*)d_out;

    // ---- workspace layout (rec first for 8B alignment) ----
    int2*  rec      = (int2*)d_ws;                      // 2*EE records
    float* dinv_in  = (float*)(rec + 2 * (size_t)EE);   // N
    float* dinv_out = dinv_in + NN;                     // N
    int*   cnt      = (int*)(dinv_out + NN);            // 2N
    int*   off      = cnt + 2 * NN;                     // 2N+1
    int*   cur      = off + 2 * NN + 1;                 // 2N
    int*   bsum     = cur + 2 * NN;                     // 256
    float* Wz       = (float*)(bsum + 256);             // 108*32
    float* Wh       = Wz + ROWS * FOUT;                 // 108*32
    float* TS       = Wh + ROWS * FOUT;                 // 8*N*12

    float* T1o = TS + (size_t)0 * NN * FIN;
    float* T2o = TS + (size_t)1 * NN * FIN;
    float* T3o = TS + (size_t)2 * NN * FIN;
    float* T4o = TS + (size_t)3 * NN * FIN;
    float* T1i = TS + (size_t)4 * NN * FIN;
    float* T2i = TS + (size_t)5 * NN * FIN;
    float* T3i = TS + (size_t)6 * NN * FIN;
    float* T4i = TS + (size_t)7 * NN * FIN;

    dim3 B(256);
    int nbE = (EE + 255) / 256;
    int nScan = 2 * NN;
    int nbS = (nScan + 1023) / 1024;          // 196 scan blocks (<=256 for scan2)
    int nbG = (6 * NN + 255) / 256;           // gather blocks (600k threads)

    k_zero<<<(2 * NN + 255) / 256, B, 0, stream>>>(cnt, 2 * NN);
    k_cnt<<<nbE, B, 0, stream>>>(ei, cnt);

    k_scan1<<<nbS, 1024, 0, stream>>>(cnt, off, bsum, nScan);
    k_scan2<<<1, 256, 0, stream>>>(bsum, off, nScan, nbS);
    k_scan3<<<nbS, 1024, 0, stream>>>(off, cur, bsum, nScan);
    k_fill<<<nbE, B, 0, stream>>>(ei, ew, cur, rec);

    k_degsum<<<(2 * NN + 255) / 256, B, 0, stream>>>(off, rec, dinv_in, dinv_out);
    k_coef<<<nbE, B, 0, stream>>>(rec, dinv_out);

    k_buildw<<<(2 * ROWS * FOUT + 255) / 256, B, 0, stream>>>(W_z, W_h, Wz, Wh);

    // Chebyshev diffusion basis via gather (atomic-free)
    k_gather<<<nbG, B, 0, stream>>>(off, rec, x, x, nullptr, nullptr, dinv_in, T1o, T1i, 1.f);
    k_gather<<<nbG, B, 0, stream>>>(off, rec, T1o, T1i, x, x, dinv_in, T2o, T2i, 2.f);
    k_gather<<<nbG, B, 0, stream>>>(off, rec, T2o, T2i, T1o, T1i, dinv_in, T3o, T3i, 2.f);
    k_gather<<<nbG, B, 0, stream>>>(off, rec, T3o, T3i, T2o, T2i, dinv_in, T4o, T4i, 2.f);

    k_init_out<<<(GG * CC + 255) / 256, B, 0, stream>>>(out, b_lin);
    k_fused<<<4 * GG, B, 0, stream>>>(x, TS, Wz, Wh, b_z, b_h, W_lin, out);
}

// Round 4
// 721.134 us; speedup vs baseline: 11.0487x; 1.3049x over previous
//
#include <hip/hip_runtime.h>
#include <math.h>

#define NN   100000
#define GG   100
#define FIN  12
#define FOUT 32
#define KD   5
#define CC   4
#define EE   1600000
#define ROWS 108          // 9 blocks * 12 features

// ---------------- CSR build ----------------

__global__ void k_zero(int* __restrict__ p, int n) {
    int i = blockIdx.x * 256 + threadIdx.x;
    if (i < n) p[i] = 0;
}

// CSR bucket counts; the atomic return value IS the edge's rank in its bucket
// (stored coalesced, consumed by the atomic-free k_fill).
// fwd CSR keyed by dst (gather for prop_fwd), rev CSR keyed by src.
__global__ void k_cnt(const int* __restrict__ ei, int* __restrict__ cnt,
                      int* __restrict__ rankF, int* __restrict__ rankR) {
    int e = blockIdx.x * 256 + threadIdx.x;
    if (e >= EE) return;
    int s = ei[e];
    int d = ei[EE + e];
    rankF[e] = atomicAdd(cnt + d, 1);       // fwd: in-edges of dst
    rankR[e] = atomicAdd(cnt + NN + s, 1);  // rev: out-edges of src
}

// ---- 3-kernel exclusive scan over cnt[0..n) -> off[0..n], off[n]=total ----

__global__ __launch_bounds__(1024) void k_scan1(const int* __restrict__ cnt,
                                                int* __restrict__ off,
                                                int* __restrict__ bsum, int n) {
    __shared__ int sh[1024];
    int t = threadIdx.x;
    int i = blockIdx.x * 1024 + t;
    int v = (i < n) ? cnt[i] : 0;
    sh[t] = v;
    __syncthreads();
    for (int d = 1; d < 1024; d <<= 1) {
        int x = sh[t];
        if (t >= d) x += sh[t - d];
        __syncthreads();
        sh[t] = x;
        __syncthreads();
    }
    int incl = sh[t];
    if (i < n) off[i] = incl - v;          // block-local exclusive
    if (t == 1023) bsum[blockIdx.x] = incl;
}

__global__ __launch_bounds__(256) void k_scan2(int* __restrict__ bsum,
                                               int* __restrict__ off, int n, int nb) {
    __shared__ int sh[256];
    int t = threadIdx.x;
    int v = (t < nb) ? bsum[t] : 0;
    sh[t] = v;
    __syncthreads();
    for (int d = 1; d < 256; d <<= 1) {
        int x = sh[t];
        if (t >= d) x += sh[t - d];
        __syncthreads();
        sh[t] = x;
        __syncthreads();
    }
    int incl = sh[t];
    if (t < nb) bsum[t] = incl - v;        // exclusive block base
    if (t == nb - 1) off[n] = incl;        // grand total (= 2*EE)
}

__global__ __launch_bounds__(1024) void k_scan3(int* __restrict__ off,
                                                const int* __restrict__ bsum, int n) {
    int i = blockIdx.x * 1024 + threadIdx.x;
    if (i < n) off[i] += bsum[blockIdx.x];
}

// Atomic-free CSR fill: position = off[bucket] + rank (rank from k_cnt).
__global__ void k_fill(const int* __restrict__ ei, const float* __restrict__ ew,
                       const int* __restrict__ off,
                       const int* __restrict__ rankF, const int* __restrict__ rankR,
                       int2* __restrict__ rec) {
    int e = blockIdx.x * 256 + threadIdx.x;
    if (e >= EE) return;
    int s = ei[e];
    int d = ei[EE + e];
    float w = ew[e];
    rec[off[d] + rankF[e]]      = make_int2(s, __float_as_int(w));
    rec[off[NN + s] + rankR[e]] = make_int2(d, __float_as_int(w));
}

// Atomic-free degree sums from the CSR buckets:
//   fwd bucket of n (in-edges)  -> deg_in[n];  rev bucket of n (out-edges) -> deg_out[n]
__global__ void k_degsum(const int* __restrict__ off, const int2* __restrict__ rec,
                         float* __restrict__ dinv_in, float* __restrict__ dinv_out) {
    int i = blockIdx.x * 256 + threadIdx.x;
    if (i >= 2 * NN) return;
    int e0 = off[i], e1 = off[i + 1];
    const float* rf = (const float*)rec;
    float s = 0.f;
    for (int e = e0; e < e1; ++e) s += rf[2 * e + 1];
    float inv = 1.f / s;
    if (i < NN) dinv_in[i] = inv;
    else        dinv_out[i - NN] = inv;
}

// Rewrite fwd-region records' payload to the propagation coefficient 1/deg_out[src].
// Fwd region is statically rec[0..EE): every edge contributes exactly one fwd record.
// (Rev coefficient 1/deg_in[node] is uniform per output node -> applied in gather epilogue.)
__global__ void k_coef(int2* __restrict__ rec, const float* __restrict__ dinv_out) {
    int e = blockIdx.x * 256 + threadIdx.x;
    if (e >= EE) return;
    rec[e].y = __float_as_int(dinv_out[rec[e].x]);
}

// ---------------- weights ----------------

// Collapse W[2,K,44,32] -> effective [108,32] (only first 12 input rows matter;
// block 0 = W[0,0]+W[1,0]; blocks 1..4 = W[0,k]; blocks 5..8 = W[1,k]).
__global__ void k_buildw(const float* __restrict__ Wz_in, const float* __restrict__ Wh_in,
                         float* __restrict__ Wz, float* __restrict__ Wh) {
    int t = blockIdx.x * 256 + threadIdx.x;
    if (t >= 2 * ROWS * FOUT) return;
    int sel = t / (ROWS * FOUT);
    int rem = t - sel * ROWS * FOUT;
    int r = rem / FOUT;
    int f = rem - r * FOUT;
    int b = r / 12;
    int i = r - b * 12;
    const float* Ws = sel ? Wh_in : Wz_in;
    float v;
    if (b == 0)
        v = Ws[(0 * KD + 0) * 44 * 32 + i * 32 + f] + Ws[(1 * KD + 0) * 44 * 32 + i * 32 + f];
    else if (b <= 4)
        v = Ws[(0 * KD + b) * 44 * 32 + i * 32 + f];
    else
        v = Ws[(1 * KD + (b - 4)) * 44 * 32 + i * 32 + f];
    (sel ? Wh : Wz)[r * FOUT + f] = v;
}

// ---------------- diffusion gather ----------------

// Thread per (node, direction, 4-feature chunk): 6N threads total.
// fwd: out[n] = c * sum_{in-edges} coef(src) * in[src]        - prev[n]
// rev: out[n] = c * dinv_in[n] * sum_{out-edges} in[dst]      - prev[n]
__global__ __launch_bounds__(256) void k_gather(
        const int* __restrict__ off, const int2* __restrict__ rec,
        const float* __restrict__ inF, const float* __restrict__ inR,
        const float* __restrict__ prevF, const float* __restrict__ prevR,
        const float* __restrict__ dinv_in,
        float* __restrict__ outF, float* __restrict__ outR, float c) {
    int gid = blockIdx.x * 256 + threadIdx.x;
    if (gid >= 6 * NN) return;
    bool rev = gid >= 3 * NN;
    int t = rev ? gid - 3 * NN : gid;
    int node = t / 3;
    int ch = t - node * 3;
    int b = rev ? NN + node : node;
    int e0 = off[b], e1 = off[b + 1];

    float ax = 0.f, ay = 0.f, az = 0.f, aw = 0.f;
    if (rev) {
        const int* rx = (const int*)rec;
        for (int e = e0; e < e1; ++e) {
            int nbr = rx[2 * e];
            float4 v = *(const float4*)(inR + (size_t)nbr * FIN + ch * 4);
            ax += v.x; ay += v.y; az += v.z; aw += v.w;
        }
        float sc = c * dinv_in[node];
        ax *= sc; ay *= sc; az *= sc; aw *= sc;
    } else {
        for (int e = e0; e < e1; ++e) {
            int2 r = rec[e];
            float w = __int_as_float(r.y);
            float4 v = *(const float4*)(inF + (size_t)r.x * FIN + ch * 4);
            ax = fmaf(w, v.x, ax); ay = fmaf(w, v.y, ay);
            az = fmaf(w, v.z, az); aw = fmaf(w, v.w, aw);
        }
        ax *= c; ay *= c; az *= c; aw *= c;
    }

    size_t o = (size_t)node * FIN + ch * 4;
    float4 res;
    if (prevF) {
        float4 p = *(const float4*)((rev ? prevR : prevF) + o);
        res = make_float4(ax - p.x, ay - p.y, az - p.z, aw - p.w);
    } else {
        res = make_float4(ax, ay, az, aw);
    }
    *(float4*)((rev ? outR : outF) + o) = res;
}

// ---------------- epilogue ----------------

__global__ void k_init_out(float* __restrict__ out, const float* __restrict__ b_lin) {
    int t = blockIdx.x * 256 + threadIdx.x;
    if (t < GG * CC) out[t] = b_lin[t & 3];
}

// Per-node: [1x108] @ [108x32] for z and h_tilde, gate, ReLU, @W_lin,
// block-reduce over 250 nodes (each block owns 1/4 of one graph) -> atomicAdd.
__global__ __launch_bounds__(256) void k_fused(
        const float* __restrict__ x, const float* __restrict__ TS,
        const float* __restrict__ Wz, const float* __restrict__ Wh,
        const float* __restrict__ bz, const float* __restrict__ bh,
        const float* __restrict__ Wlin, float* __restrict__ out) {
    int g = blockIdx.x >> 2;
    int seg = blockIdx.x & 3;
    int tid = threadIdx.x;
    int node = g * 1000 + seg * 250 + tid;
    bool active = tid < 250;

    float az[FOUT], ah[FOUT];
#pragma unroll
    for (int f = 0; f < FOUT; ++f) { az[f] = bz[f]; ah[f] = bh[f]; }
    float o[CC] = {0.f, 0.f, 0.f, 0.f};

    if (active) {
        for (int b = 0; b < 9; ++b) {
            const float* row = (b == 0) ? (x + (size_t)node * FIN)
                                        : (TS + ((size_t)(b - 1) * NN + node) * FIN);
            float4 r0 = *(const float4*)(row);
            float4 r1 = *(const float4*)(row + 4);
            float4 r2 = *(const float4*)(row + 8);
            float rv[FIN] = {r0.x, r0.y, r0.z, r0.w, r1.x, r1.y, r1.z, r1.w,
                             r2.x, r2.y, r2.z, r2.w};
            const float* wzr = Wz + b * 12 * FOUT;
            const float* whr = Wh + b * 12 * FOUT;
#pragma unroll
            for (int i = 0; i < FIN; ++i) {
                float v = rv[i];
#pragma unroll
                for (int f = 0; f < FOUT; ++f) {
                    az[f] = fmaf(v, wzr[i * FOUT + f], az[f]);
                    ah[f] = fmaf(v, whr[i * FOUT + f], ah[f]);
                }
            }
        }
#pragma unroll
        for (int f = 0; f < FOUT; ++f) {
            float z = 1.f / (1.f + __expf(-az[f]));
            float e2 = __expf(2.f * ah[f]);
            float th = 1.f - 2.f / (e2 + 1.f);   // tanh, overflow-safe
            float hv = (1.f - z) * th;
            hv = fmaxf(hv, 0.f);
#pragma unroll
            for (int c = 0; c < CC; ++c) o[c] = fmaf(hv, Wlin[f * 4 + c], o[c]);
        }
    }

    __shared__ float red[256 * CC];
#pragma unroll
    for (int c = 0; c < CC; ++c) red[tid * CC + c] = o[c];
    __syncthreads();
    for (int st = 128; st > 0; st >>= 1) {
        if (tid < st) {
#pragma unroll
            for (int c = 0; c < CC; ++c) red[tid * CC + c] += red[(tid + st) * CC + c];
        }
        __syncthreads();
    }
    if (tid == 0) {
#pragma unroll
        for (int c = 0; c < CC; ++c) atomicAdd(out + g * CC + c, red[c] * 0.001f);
    }
}

// ---------------- launch ----------------

extern "C" void kernel_launch(void* const* d_in, const int* in_sizes, int n_in,
                              void* d_out, int out_size, void* d_ws, size_t ws_size,
                              hipStream_t stream) {
    const float* x     = (const float*)d_in[0];
    const int*   ei    = (const int*)d_in[1];
    const float* ew    = (const float*)d_in[2];
    // d_in[3] (batch) unused: graphs are exactly 1000 contiguous nodes
    const float* W_z   = (const float*)d_in[4];
    const float* b_z   = (const float*)d_in[5];
    // d_in[6], d_in[7] (W_r, b_r) unused: R only multiplies the zero hidden state
    const float* W_h   = (const float*)d_in[8];
    const float* b_h   = (const float*)d_in[9];
    const float* W_lin = (const float*)d_in[10];
    const float* b_lin = (const float*)d_in[11];
    float* out = (float*)d_out;

    // ---- workspace layout (rec first for 8B alignment) ----
    int2*  rec      = (int2*)d_ws;                      // 2*EE records
    float* dinv_in  = (float*)(rec + 2 * (size_t)EE);   // N
    float* dinv_out = dinv_in + NN;                     // N
    int*   cnt      = (int*)(dinv_out + NN);            // 2N
    int*   off      = cnt + 2 * NN;                     // 2N+1
    int*   bsum     = off + 2 * NN + 1;                 // 256
    float* Wz       = (float*)(bsum + 256);             // 108*32
    float* Wh       = Wz + ROWS * FOUT;                 // 108*32
    float* TS       = Wh + ROWS * FOUT;                 // 8*N*12

    float* T1o = TS + (size_t)0 * NN * FIN;
    float* T2o = TS + (size_t)1 * NN * FIN;
    float* T3o = TS + (size_t)2 * NN * FIN;
    float* T4o = TS + (size_t)3 * NN * FIN;
    float* T1i = TS + (size_t)4 * NN * FIN;
    float* T2i = TS + (size_t)5 * NN * FIN;
    float* T3i = TS + (size_t)6 * NN * FIN;
    float* T4i = TS + (size_t)7 * NN * FIN;

    // Rank arrays alias TS (dead before first k_gather writes T1): 2*EE ints = 12.8 MB
    int* rankF = (int*)TS;
    int* rankR = rankF + EE;

    dim3 B(256);
    int nbE = (EE + 255) / 256;
    int nScan = 2 * NN;
    int nbS = (nScan + 1023) / 1024;          // 196 scan blocks (<=256 for scan2)
    int nbG = (6 * NN + 255) / 256;           // gather blocks (600k threads)

    k_zero<<<(2 * NN + 255) / 256, B, 0, stream>>>(cnt, 2 * NN);
    k_cnt<<<nbE, B, 0, stream>>>(ei, cnt, rankF, rankR);

    k_scan1<<<nbS, 1024, 0, stream>>>(cnt, off, bsum, nScan);
    k_scan2<<<1, 256, 0, stream>>>(bsum, off, nScan, nbS);
    k_scan3<<<nbS, 1024, 0, stream>>>(off, bsum, nScan);
    k_fill<<<nbE, B, 0, stream>>>(ei, ew, off, rankF, rankR, rec);

    k_degsum<<<(2 * NN + 255) / 256, B, 0, stream>>>(off, rec, dinv_in, dinv_out);
    k_coef<<<nbE, B, 0, stream>>>(rec, dinv_out);

    k_buildw<<<(2 * ROWS * FOUT + 255) / 256, B, 0, stream>>>(W_z, W_h, Wz, Wh);

    // Chebyshev diffusion basis via gather (atomic-free)
    k_gather<<<nbG, B, 0, stream>>>(off, rec, x, x, nullptr, nullptr, dinv_in, T1o, T1i, 1.f);
    k_gather<<<nbG, B, 0, stream>>>(off, rec, T1o, T1i, x, x, dinv_in, T2o, T2i, 2.f);
    k_gather<<<nbG, B, 0, stream>>>(off, rec, T2o, T2i, T1o, T1i, dinv_in, T3o, T3i, 2.f);
    k_gather<<<nbG, B, 0, stream>>>(off, rec, T3o, T3i, T2o, T2i, dinv_in, T4o, T4i, 2.f);

    k_init_out<<<(GG * CC + 255) / 256, B, 0, stream>>>(out, b_lin);
    k_fused<<<4 * GG, B, 0, stream>>>(x, TS, Wz, Wh, b_z, b_h, W_lin, out);
}